// Round 6
// baseline (812.461 us; speedup 1.0000x reference)
//
#include <hip/hip_runtime.h>

// MON forward-backward splitting via Anderson acceleration, MI355X/gfx950.
// R5: 512 blocks x 512 threads (2-row tiles), LDS 39.5KB -> 2 blocks/CU overlap.
//     Fh/G stored packed-linear [slot][block][tid][16]: contiguous 64B stores
//     (kills write amplification), vectorized FX own reads. z in registers.
//     Halo rows gathered via strided scalar reads. XCD-chunked block swizzle.

typedef unsigned short u16;
using short8 = __attribute__((ext_vector_type(8))) short;
using f32x4  = __attribute__((ext_vector_type(4))) float;

#define SLOT 4194304              // elements per history slot (512 blk * 512 thr * 16)

struct Ctrl { int done; int last_slot; };

__device__ __forceinline__ u16 f2bf(float f) {
  unsigned u = __builtin_bit_cast(unsigned, f);
  unsigned r = (u + 0x7FFFu + ((u >> 16) & 1u)) >> 16;   // RNE, finite inputs
  return (u16)r;
}
__device__ __forceinline__ float bf2f(u16 h) {
  unsigned u = ((unsigned)h) << 16;
  return __builtin_bit_cast(float, u);
}

// ---------------- W[cout][cin][ky][kx] f32 -> Wb[o][cout][cin] bf16; ctrl init
__global__ void __launch_bounds__(256) k_prepw(const float* __restrict__ W,
    u16* __restrict__ Wb, Ctrl* ctrl) {
  if (blockIdx.x == 0 && threadIdx.x == 0) { ctrl->done = 0; ctrl->last_slot = 4; }
  int t = blockIdx.x * 256 + threadIdx.x;       // 9*128*128 threads
  int o = t >> 14;
  int rem = t & 16383;
  int cout = rem >> 7, cin = rem & 127;
  float v = W[(size_t)cout * 1152 + (size_t)cin * 9 + o];
  Wb[(size_t)o * 16384 + (size_t)cout * 128 + cin] = f2bf(v);
}

// ---------------- x NCHW f32 -> xsw bf16 swizzled NHWC
__global__ void __launch_bounds__(256) k_prepx(const float* __restrict__ x,
    u16* __restrict__ xsw) {
  int t = blockIdx.x * 256 + threadIdx.x;       // 524288 threads
  int g = t >> 15, p = t & 32767;
  int nb = p >> 10, gp = p & 1023, px = p & 31;
  short8 xv;
#pragma unroll
  for (int u = 0; u < 8; ++u) {
    float v = x[(size_t)nb * 131072 + (size_t)(g * 8 + u) * 1024 + gp];
    xv[u] = (short)f2bf(v);
  }
  *(short8*)(xsw + (size_t)p * 128 + (size_t)((g ^ (px & 7)) << 3)) = xv;
}

// ---------------- one Anderson iteration, fully fused ----------------
// 512 blocks x 512 threads; logical block lbid = 2-row strip (n = lbid>>4, y0 = (lbid&15)*2).
// Thread owns 16 (pixel,channel) elems in the MFMA C/D mapping; z kept in registers.
// Packed layout: elem (slot, lbid, tid, m2*4+rr) <-> pixel p=m2*16+lhi*4+rr, ch=wc*16+llo.
__global__ void __launch_bounds__(512, 8) k_iter(
    const int e,
    const u16* __restrict__ xsw, const int* __restrict__ mask_,
    const u16* __restrict__ Wb, const float* __restrict__ bias,
    float* __restrict__ Fhp, u16* __restrict__ Gp,
    float* __restrict__ gram, float* __restrict__ gpart,
    float* __restrict__ resp, Ctrl* __restrict__ ctrl)
{
  __shared__ char smem[39552];
  char*  As       = smem;                        // 4 rows * 34 cols * 256B = 34816
  float* rowmax_s = (float*)(smem + 34816);      // [64][8] = 2048
  float* rowsum_s = (float*)(smem + 36864);      // 2048
  float* red      = (float*)(smem + 38912);      // 8 waves * 8 = 256
  float* alpha_s  = (float*)(smem + 39168);      // 5
  float* res_s    = (float*)(smem + 39188);      // 1
  int*   mk_s     = (int*)(smem + 39296);        // 64

  if (ctrl->done) return;

  const int tid = threadIdx.x;
  const int wc = tid >> 6, lane = tid & 63;
  const int lhi = lane >> 4, llo = lane & 15;
  const int bhw = blockIdx.x;
  const int lbid = ((bhw & 7) << 6) + (bhw >> 3);    // XCD chunk swizzle (512=8*64)
  const int n = lbid >> 4, y0 = (lbid & 15) << 1;
  const int gpix0 = (n << 10) + (y0 << 5);
  const int colc = (wc << 4) + llo;
  const int slot = e % 5;
  const int nact = e < 5 ? e : 5;
  const size_t base = ((size_t)lbid * 512 + tid) * 16;

  // ---- res gate (cond before body e uses res of eval e-1) ----
  if (e >= 3) {
    if (tid < 64) {
      float sd = 0.f, sf = 0.f;
      for (int i = tid; i < 512; i += 64) { sd += resp[2 * i]; sf += resp[2 * i + 1]; }
#pragma unroll
      for (int off = 1; off < 64; off <<= 1) { sd += __shfl_xor(sd, off); sf += __shfl_xor(sf, off); }
      if (tid == 0) res_s[0] = sqrtf(sd) / (1e-5f + sqrtf(sf));
    }
    __syncthreads();
    if (res_s[0] < 1e-5f) {                      // identical decision in every block
      if (tid == 0) { ctrl->done = 1; ctrl->last_slot = (e - 1) % 5; }
      return;
    }
  }

  // ---- masks for own 64 px; fold gram row/col of slot (e-1)%5 ----
  if (tid < 64) mk_s[tid] = mask_[gpix0 + tid];
  if (e >= 1 && tid >= 64 && tid < 69) {
    int j = tid - 64;
    float s = 0.f;
#pragma unroll
    for (int c = 0; c < 16; ++c) s += gpart[(size_t)((n << 4) + c) * 5 + j];
    int sp = (e - 1) % 5;
    gram[n * 25 + sp * 5 + j] = s;               // all 16 blocks of image n write
    gram[n * 25 + j * 5 + sp] = s;               // identical values: benign
  }
  __syncthreads();
  if (e >= 2) {
    if (tid == 0) {                              // bordered 6x6 solve, f32 GE w/ pivot
      float A[6][7];
      for (int i = 0; i < 5; ++i)
        for (int j = 0; j < 5; ++j)
          A[i + 1][j + 1] = (i < nact && j < nact)
              ? gram[n * 25 + i * 5 + j] + ((i == j) ? 1e-4f : 0.f)
              : ((i == j) ? 1.f : 0.f);
      A[0][0] = 0.f;
      for (int j = 0; j < 5; ++j) { float aj = (j < nact) ? 1.f : 0.f; A[0][j + 1] = aj; A[j + 1][0] = aj; }
      A[0][6] = 1.f;
      for (int i = 1; i < 6; ++i) A[i][6] = 0.f;
      for (int c = 0; c < 6; ++c) {
        int p = c; float mx = fabsf(A[c][c]);
        for (int r = c + 1; r < 6; ++r) { float v = fabsf(A[r][c]); if (v > mx) { mx = v; p = r; } }
        if (p != c) for (int q = c; q < 7; ++q) { float tmp = A[c][q]; A[c][q] = A[p][q]; A[p][q] = tmp; }
        float piv = A[c][c];
        for (int r = c + 1; r < 6; ++r) {
          float fr = A[r][c] / piv;
          for (int q = c; q < 7; ++q) A[r][q] -= fr * A[c][q];
        }
      }
      float sol[6];
      for (int r = 5; r >= 0; --r) {
        float s = A[r][6];
        for (int q = r + 1; q < 6; ++q) s -= A[r][q] * sol[q];
        sol[r] = s / A[r][r];
      }
      for (int j = 0; j < 5; ++j) alpha_s[j] = sol[j + 1];
    }
  } else if (tid < 5) {
    alpha_s[tid] = (tid == 0) ? 1.f : 0.f;       // e==1: xnew = F0 (e==0 ignores)
  }
  __syncthreads();

  float a0 = 1.f, a1 = 0.f, a2 = 0.f, a3 = 0.f, a4 = 0.f;
  if (e >= 1) { a0 = alpha_s[0]; a1 = alpha_s[1]; a2 = alpha_s[2]; a3 = alpha_s[3]; a4 = alpha_s[4]; }

  // ---- FX own: z = sum_j alpha_j Fh_j, vectorized from packed layout ----
  f32x4 zv[4];
  if (e == 0) {
    const f32x4 cz = {0.0078125f, 0.0078125f, 0.0078125f, 0.0078125f};
    zv[0] = cz; zv[1] = cz; zv[2] = cz; zv[3] = cz;
  } else {
    const float* fb = Fhp + base;
#pragma unroll
    for (int q = 0; q < 4; ++q) zv[q] = a0 * *(const f32x4*)(fb + q * 4);
    if (nact > 1) {
#pragma unroll
      for (int q = 0; q < 4; ++q) zv[q] += a1 * *(const f32x4*)(fb + SLOT + q * 4);
    }
    if (nact > 2) {
#pragma unroll
      for (int q = 0; q < 4; ++q) zv[q] += a2 * *(const f32x4*)(fb + 2 * SLOT + q * 4);
    }
    if (nact > 3) {
#pragma unroll
      for (int q = 0; q < 4; ++q) zv[q] += a3 * *(const f32x4*)(fb + 3 * SLOT + q * 4);
    }
    if (nact > 4) {
#pragma unroll
      for (int q = 0; q < 4; ++q) zv[q] += a4 * *(const f32x4*)(fb + 4 * SLOT + q * 4);
    }
  }

  // ---- own-row staging: mask-merged bf16 scatter into swizzled A-tile ----
#pragma unroll
  for (int m2 = 0; m2 < 4; ++m2)
#pragma unroll
    for (int rr = 0; rr < 4; ++rr) {
      int p = (m2 << 4) + (lhi << 2) + rr;       // elem index m2*4+rr <-> pixel p
      int px = p & 31, row = 1 + (p >> 5);
      int sg = (colc >> 3) ^ (px & 7);
      u16 w;
      if (mk_s[p])
        w = xsw[(size_t)(gpix0 + p) * 128 + (sg << 3) + (colc & 7)];
      else
        w = f2bf(zv[m2][rr]);
      *(u16*)(As + row * 8704 + ((px + 1) << 8) + (sg << 4) + ((colc & 7) << 1)) = w;
    }

  // ---- halo staging: rows y0-1 and y0+2, strided gather from packed layout ----
#pragma unroll
  for (int uu = 0; uu < 2; ++uu) {
    int u = (uu << 9) + tid;
    int rsel = u >> 9;
    int row = rsel * 3;                          // tile row 0 or 3
    int gy = y0 - 1 + row;
    int idx = u & 511;
    int px = idx >> 4, grp = idx & 15;
    char* dst = As + row * 8704 + ((px + 1) << 8) + ((grp ^ (px & 7)) << 4);
    short8 w = {0, 0, 0, 0, 0, 0, 0, 0};
    if ((unsigned)gy < 32u) {
      int gpix = (n << 10) + (gy << 5) + px;
      if (mask_[gpix]) {
        w = *(const short8*)(xsw + (size_t)gpix * 128 + ((grp ^ (px & 7)) << 3));
      } else if (e == 0) {
#pragma unroll
        for (int i = 0; i < 8; ++i) w[i] = (short)0x3C00;   // bf16(1/128)
      } else {
        int bidh = (n << 4) + (gy >> 1);
        int pl = ((gy & 1) << 5) + px;
        int elem = ((pl >> 4) << 2) + (pl & 3);
        int tb = ((grp >> 1) << 6) + (((pl >> 2) & 3) << 4) + ((grp & 1) << 3);
        const float* fb2 = Fhp + ((size_t)bidh * 512 + tb) * 16 + elem;
#pragma unroll
        for (int i = 0; i < 8; ++i) {
          float s = a0 * fb2[i * 16];
          if (nact > 1) s += a1 * fb2[SLOT + i * 16];
          if (nact > 2) s += a2 * fb2[2 * SLOT + i * 16];
          if (nact > 3) s += a3 * fb2[3 * SLOT + i * 16];
          if (nact > 4) s += a4 * fb2[4 * SLOT + i * 16];
          w[i] = (short)f2bf(s);
        }
      }
    }
    *(short8*)dst = w;
  }
  if (tid < 128) {                               // zero pads: cols 0 and 33, 4 rows
    int r = tid >> 5, cc = tid & 31;
    int col = (cc < 16) ? 0 : 33, gc = cc & 15;
    f32x4 zz = {0.f, 0.f, 0.f, 0.f};
    *(f32x4*)(As + r * 8704 + (col << 8) + (gc << 4)) = zz;
  }
  __syncthreads();

  // ---- CONV: 144 MFMAs/wave off the LDS tile; B frags from global (L2-hot) ----
  f32x4 acc[4];
  {
    const f32x4 z4 = {0.f, 0.f, 0.f, 0.f};
    acc[0] = z4; acc[1] = z4; acc[2] = z4; acc[3] = z4;
  }
#pragma unroll
  for (int o = 0; o < 9; ++o) {
    const int dy = o / 3, dx = o % 3;
    short8 bfr[4];
#pragma unroll
    for (int kk = 0; kk < 4; ++kk)
      bfr[kk] = *(const short8*)(Wb + o * 16384 + colc * 128 + ((kk << 2) + lhi) * 8);
#pragma unroll
    for (int kk = 0; kk < 4; ++kk) {
      const int kg = (kk << 2) + lhi;
#pragma unroll
      for (int m2 = 0; m2 < 4; ++m2) {
        int p = (m2 << 4) + llo;
        int r = (p >> 5) + dy, cl = (p & 31) + dx;
        int sg = kg ^ ((cl - 1) & 7);
        short8 af = *(const short8*)(As + r * 8704 + (cl << 8) + (sg << 4));
        acc[m2] = __builtin_amdgcn_mfma_f32_16x16x32_bf16(af, bfr[kk], acc[m2], 0, 0, 0);
      }
    }
  }

  // ---- epilogue: damp, channel-softmax(128), fnew, G, gram/res partials ----
  const float bc = bias[colc];
#pragma unroll
  for (int m2 = 0; m2 < 4; ++m2)
#pragma unroll
    for (int rr = 0; rr < 4; ++rr)
      acc[m2][rr] = 0.1f * zv[m2][rr] + 0.9f * (acc[m2][rr] + bc);
#pragma unroll
  for (int m2 = 0; m2 < 4; ++m2)
#pragma unroll
    for (int rr = 0; rr < 4; ++rr) {
      float v = acc[m2][rr];
      v = fmaxf(v, __shfl_xor(v, 1)); v = fmaxf(v, __shfl_xor(v, 2));
      v = fmaxf(v, __shfl_xor(v, 4)); v = fmaxf(v, __shfl_xor(v, 8));
      if (llo == 0) rowmax_s[((m2 << 4) + (lhi << 2) + rr) * 8 + wc] = v;
    }
  __syncthreads();
#pragma unroll
  for (int m2 = 0; m2 < 4; ++m2)
#pragma unroll
    for (int rr = 0; rr < 4; ++rr) {
      int p = (m2 << 4) + (lhi << 2) + rr;
      f32x4 m0 = *(const f32x4*)&rowmax_s[p * 8];
      f32x4 m1 = *(const f32x4*)&rowmax_s[p * 8 + 4];
      float M = fmaxf(fmaxf(fmaxf(m0[0], m0[1]), fmaxf(m0[2], m0[3])),
                      fmaxf(fmaxf(m1[0], m1[1]), fmaxf(m1[2], m1[3])));
      float ev = __expf(acc[m2][rr] - M);
      acc[m2][rr] = ev;
      float s = ev;
      s += __shfl_xor(s, 1); s += __shfl_xor(s, 2);
      s += __shfl_xor(s, 4); s += __shfl_xor(s, 8);
      if (llo == 0) rowsum_s[p * 8 + wc] = s;
    }
  __syncthreads();

  float sd = 0.f, sf = 0.f;
  float gd16[16];
#pragma unroll
  for (int m2 = 0; m2 < 4; ++m2) {
    f32x4 fr;
#pragma unroll
    for (int rr = 0; rr < 4; ++rr) {
      int p = (m2 << 4) + (lhi << 2) + rr;
      f32x4 s0 = *(const f32x4*)&rowsum_s[p * 8];
      f32x4 s1 = *(const f32x4*)&rowsum_s[p * 8 + 4];
      float S = s0[0] + s0[1] + s0[2] + s0[3] + s1[0] + s1[1] + s1[2] + s1[3];
      float fnew = acc[m2][rr] * (1.0f / S);
      fr[rr] = fnew;
      float gd = fnew - zv[m2][rr];
      gd16[m2 * 4 + rr] = gd;
      sd += gd * gd; sf += fnew * fnew;
    }
    *(f32x4*)(Fhp + (size_t)slot * SLOT + base + m2 * 4) = fr;   // 64B/thread total
  }
  {
    short8 h0, h1;
#pragma unroll
    for (int i = 0; i < 8; ++i) { h0[i] = (short)f2bf(gd16[i]); h1[i] = (short)f2bf(gd16[8 + i]); }
    u16* Gs = Gp + (size_t)slot * SLOT + base;
    *(short8*)(Gs) = h0;
    *(short8*)(Gs + 8) = h1;
    const int jmax = e < 4 ? e : 4;              // valid slots this iteration
    float gacc[5];
#pragma unroll
    for (int j = 0; j < 5; ++j) {
      if (j > jmax) { gacc[j] = 0.f; continue; }
      if (j == slot) {
        float a = 0.f;
#pragma unroll
        for (int i = 0; i < 16; ++i) a += gd16[i] * gd16[i];
        gacc[j] = a;
      } else {
        short8 q0 = *(const short8*)(Gp + (size_t)j * SLOT + base);
        short8 q1 = *(const short8*)(Gp + (size_t)j * SLOT + base + 8);
        float a = 0.f;
#pragma unroll
        for (int i = 0; i < 8; ++i)
          a += gd16[i] * bf2f((u16)q0[i]) + gd16[8 + i] * bf2f((u16)q1[i]);
        gacc[j] = a;
      }
    }
    float vals[7] = {gacc[0], gacc[1], gacc[2], gacc[3], gacc[4], sd, sf};
#pragma unroll
    for (int i = 0; i < 7; ++i) {
      float v = vals[i];
#pragma unroll
      for (int off = 1; off < 64; off <<= 1) v += __shfl_xor(v, off);
      if (lane == 0) red[wc * 8 + i] = v;
    }
  }
  __syncthreads();
  if (tid < 7) {
    float s = 0.f;
#pragma unroll
    for (int w = 0; w < 8; ++w) s += red[w * 8 + tid];
    if (tid < 5)       gpart[(size_t)lbid * 5 + tid] = s;
    else if (tid == 5) resp[lbid * 2] = s;
    else               resp[lbid * 2 + 1] = s;
  }
}

// ---------------- final: Fhp[last_slot] packed -> d_out NCHW f32
__global__ void __launch_bounds__(512) k_out(const float* __restrict__ Fhp,
    const Ctrl* __restrict__ ctrl, float* __restrict__ out)
{
  __shared__ float T[64 * 129];
  int slot = ctrl->last_slot;
  const int tid = threadIdx.x;
  const int wc = tid >> 6, lane = tid & 63;
  const int lhi = lane >> 4, llo = lane & 15;
  const int bhw = blockIdx.x;
  const int lbid = ((bhw & 7) << 6) + (bhw >> 3);
  const int n = lbid >> 4, y0 = (lbid & 15) << 1;
  const size_t base = (size_t)slot * SLOT + ((size_t)lbid * 512 + tid) * 16;
#pragma unroll
  for (int m2 = 0; m2 < 4; ++m2) {
    f32x4 v = *(const f32x4*)(Fhp + base + m2 * 4);
#pragma unroll
    for (int rr = 0; rr < 4; ++rr) {
      int p = (m2 << 4) + (lhi << 2) + rr;
      T[p * 129 + (wc << 4) + llo] = v[rr];
    }
  }
  __syncthreads();
  int c = tid >> 2, q = tid & 3;
  int row = q >> 1, xs = (q & 1) << 4;
  float* ob = out + (((size_t)(n << 7) + c) << 10) + ((y0 + row) << 5) + xs;
#pragma unroll
  for (int i2 = 0; i2 < 4; ++i2) {
    f32x4 v;
#pragma unroll
    for (int i = 0; i < 4; ++i) v[i] = T[((row << 5) + xs + (i2 << 2) + i) * 129 + c];
    *(f32x4*)(ob + (i2 << 2)) = v;
  }
}

extern "C" void kernel_launch(void* const* d_in, const int* in_sizes, int n_in,
                              void* d_out, int out_size, void* d_ws, size_t ws_size,
                              hipStream_t stream) {
  const float* x    = (const float*)d_in[0];   // [32,128,32,32]
  const float* W    = (const float*)d_in[1];   // [128,128,3,3]
  const float* bias = (const float*)d_in[2];   // [128]
  const int*   mask = (const int*)d_in[3];     // [32,1,32,32]
  float* out = (float*)d_out;
  char* ws = (char*)d_ws;

  float* Fhp   = (float*)(ws + 0);             // 83,886,080 (packed)
  u16*   Gp    = (u16*)(ws + 83886080);        // 41,943,040 (packed)
  u16*   xsw   = (u16*)(ws + 125829120);       // 8,388,608
  u16*   Wb    = (u16*)(ws + 134217728);       // 294,912
  float* gram  = (float*)(ws + 134512640);     // 3,200
  float* gpart = (float*)(ws + 134515840);     // 10,240
  float* resp  = (float*)(ws + 134526080);     // 4,096
  Ctrl*  ctrl  = (Ctrl*)(ws + 134530176);

  k_prepw<<<576, 256, 0, stream>>>(W, Wb, ctrl);
  k_prepx<<<2048, 256, 0, stream>>>(x, xsw);
  for (int e = 0; e < 50; ++e)
    k_iter<<<512, 512, 0, stream>>>(e, xsw, mask, Wb, bias,
                                    Fhp, Gp, gram, gpart, resp, ctrl);
  k_out<<<512, 512, 0, stream>>>(Fhp, ctrl, out);
  (void)in_sizes; (void)n_in; (void)out_size; (void)ws_size;
}

// Round 7
// 630.364 us; speedup vs baseline: 1.2889x; 1.2889x over previous
//
#include <hip/hip_runtime.h>

// MON forward-backward splitting via Anderson acceleration, MI355X/gfx950.
// R6: R5 structure with the spill fixed (__launch_bounds__(512,4): 128-VGPR cap)
//     and the halo path made coalesced via a bf16 NHWC-swizzled history copy
//     FhH[5] (written alongside packed Fhp in the epilogue). Own-path FX stays
//     exact f32 from the packed layout; halo combines bf16 slots (conv-input
//     precision only).

typedef unsigned short u16;
using short8 = __attribute__((ext_vector_type(8))) short;
using f32x4  = __attribute__((ext_vector_type(4))) float;

#define SLOT 4194304              // elements per history slot (32768 px * 128 ch)

struct Ctrl { int done; int last_slot; };

__device__ __forceinline__ u16 f2bf(float f) {
  unsigned u = __builtin_bit_cast(unsigned, f);
  unsigned r = (u + 0x7FFFu + ((u >> 16) & 1u)) >> 16;   // RNE, finite inputs
  return (u16)r;
}
__device__ __forceinline__ float bf2f(u16 h) {
  unsigned u = ((unsigned)h) << 16;
  return __builtin_bit_cast(float, u);
}

// ---------------- W[cout][cin][ky][kx] f32 -> Wb[o][cout][cin] bf16; ctrl init
__global__ void __launch_bounds__(256) k_prepw(const float* __restrict__ W,
    u16* __restrict__ Wb, Ctrl* ctrl) {
  if (blockIdx.x == 0 && threadIdx.x == 0) { ctrl->done = 0; ctrl->last_slot = 4; }
  int t = blockIdx.x * 256 + threadIdx.x;       // 9*128*128 threads
  int o = t >> 14;
  int rem = t & 16383;
  int cout = rem >> 7, cin = rem & 127;
  float v = W[(size_t)cout * 1152 + (size_t)cin * 9 + o];
  Wb[(size_t)o * 16384 + (size_t)cout * 128 + cin] = f2bf(v);
}

// ---------------- x NCHW f32 -> xsw bf16 swizzled NHWC
__global__ void __launch_bounds__(256) k_prepx(const float* __restrict__ x,
    u16* __restrict__ xsw) {
  int t = blockIdx.x * 256 + threadIdx.x;       // 524288 threads
  int g = t >> 15, p = t & 32767;
  int nb = p >> 10, gp = p & 1023, px = p & 31;
  short8 xv;
#pragma unroll
  for (int u = 0; u < 8; ++u) {
    float v = x[(size_t)nb * 131072 + (size_t)(g * 8 + u) * 1024 + gp];
    xv[u] = (short)f2bf(v);
  }
  *(short8*)(xsw + (size_t)p * 128 + (size_t)((g ^ (px & 7)) << 3)) = xv;
}

// ---------------- one Anderson iteration, fully fused ----------------
// 512 blocks x 512 threads; logical block lbid = 2-row strip (n = lbid>>4, y0 = (lbid&15)*2).
// Thread owns 16 (pixel,channel) elems in the MFMA C/D mapping; z kept in registers.
// Packed layout: elem (slot, lbid, tid, m2*4+rr) <-> pixel p=m2*16+lhi*4+rr, ch=wc*16+llo.
__global__ void __launch_bounds__(512, 4) k_iter(
    const int e,
    const u16* __restrict__ xsw, const int* __restrict__ mask_,
    const u16* __restrict__ Wb, const float* __restrict__ bias,
    float* __restrict__ Fhp, u16* __restrict__ FhH, u16* __restrict__ Gp,
    float* __restrict__ gram, float* __restrict__ gpart,
    float* __restrict__ resp, Ctrl* __restrict__ ctrl)
{
  __shared__ char smem[39552];
  char*  As       = smem;                        // 4 rows * 34 cols * 256B = 34816
  float* rowmax_s = (float*)(smem + 34816);      // [64][8] = 2048
  float* rowsum_s = (float*)(smem + 36864);      // 2048
  float* red      = (float*)(smem + 38912);      // 8 waves * 8 = 256
  float* alpha_s  = (float*)(smem + 39168);      // 5
  float* res_s    = (float*)(smem + 39188);      // 1
  int*   mk_s     = (int*)(smem + 39296);        // 64

  if (ctrl->done) return;

  const int tid = threadIdx.x;
  const int wc = tid >> 6, lane = tid & 63;
  const int lhi = lane >> 4, llo = lane & 15;
  const int bhw = blockIdx.x;
  const int lbid = ((bhw & 7) << 6) + (bhw >> 3);    // XCD chunk swizzle (512=8*64)
  const int n = lbid >> 4, y0 = (lbid & 15) << 1;
  const int gpix0 = (n << 10) + (y0 << 5);
  const int colc = (wc << 4) + llo;
  const int slot = e % 5;
  const int nact = e < 5 ? e : 5;
  const size_t base = ((size_t)lbid * 512 + tid) * 16;

  // ---- res gate (cond before body e uses res of eval e-1) ----
  if (e >= 3) {
    if (tid < 64) {
      float sd = 0.f, sf = 0.f;
      for (int i = tid; i < 512; i += 64) { sd += resp[2 * i]; sf += resp[2 * i + 1]; }
#pragma unroll
      for (int off = 1; off < 64; off <<= 1) { sd += __shfl_xor(sd, off); sf += __shfl_xor(sf, off); }
      if (tid == 0) res_s[0] = sqrtf(sd) / (1e-5f + sqrtf(sf));
    }
    __syncthreads();
    if (res_s[0] < 1e-5f) {                      // identical decision in every block
      if (tid == 0) { ctrl->done = 1; ctrl->last_slot = (e - 1) % 5; }
      return;
    }
  }

  // ---- masks for own 64 px; fold gram row/col of slot (e-1)%5 ----
  if (tid < 64) mk_s[tid] = mask_[gpix0 + tid];
  if (e >= 1 && tid >= 64 && tid < 69) {
    int j = tid - 64;
    float s = 0.f;
#pragma unroll
    for (int c = 0; c < 16; ++c) s += gpart[(size_t)((n << 4) + c) * 5 + j];
    int sp = (e - 1) % 5;
    gram[n * 25 + sp * 5 + j] = s;               // all 16 blocks of image n write
    gram[n * 25 + j * 5 + sp] = s;               // identical values: benign
  }
  __syncthreads();
  if (e >= 2) {
    if (tid == 0) {                              // bordered 6x6 solve, f32 GE w/ pivot
      float A[6][7];
      for (int i = 0; i < 5; ++i)
        for (int j = 0; j < 5; ++j)
          A[i + 1][j + 1] = (i < nact && j < nact)
              ? gram[n * 25 + i * 5 + j] + ((i == j) ? 1e-4f : 0.f)
              : ((i == j) ? 1.f : 0.f);
      A[0][0] = 0.f;
      for (int j = 0; j < 5; ++j) { float aj = (j < nact) ? 1.f : 0.f; A[0][j + 1] = aj; A[j + 1][0] = aj; }
      A[0][6] = 1.f;
      for (int i = 1; i < 6; ++i) A[i][6] = 0.f;
      for (int c = 0; c < 6; ++c) {
        int p = c; float mx = fabsf(A[c][c]);
        for (int r = c + 1; r < 6; ++r) { float v = fabsf(A[r][c]); if (v > mx) { mx = v; p = r; } }
        if (p != c) for (int q = c; q < 7; ++q) { float tmp = A[c][q]; A[c][q] = A[p][q]; A[p][q] = tmp; }
        float piv = A[c][c];
        for (int r = c + 1; r < 6; ++r) {
          float fr = A[r][c] / piv;
          for (int q = c; q < 7; ++q) A[r][q] -= fr * A[c][q];
        }
      }
      float sol[6];
      for (int r = 5; r >= 0; --r) {
        float s = A[r][6];
        for (int q = r + 1; q < 6; ++q) s -= A[r][q] * sol[q];
        sol[r] = s / A[r][r];
      }
      for (int j = 0; j < 5; ++j) alpha_s[j] = sol[j + 1];
    }
  } else if (tid < 5) {
    alpha_s[tid] = (tid == 0) ? 1.f : 0.f;       // e==1: xnew = F0 (e==0 ignores)
  }
  __syncthreads();

  float a0 = 1.f, a1 = 0.f, a2 = 0.f, a3 = 0.f, a4 = 0.f;
  if (e >= 1) { a0 = alpha_s[0]; a1 = alpha_s[1]; a2 = alpha_s[2]; a3 = alpha_s[3]; a4 = alpha_s[4]; }

  // ---- FX own: z = sum_j alpha_j Fh_j, vectorized from packed layout ----
  f32x4 zv[4];
  if (e == 0) {
    const f32x4 cz = {0.0078125f, 0.0078125f, 0.0078125f, 0.0078125f};
    zv[0] = cz; zv[1] = cz; zv[2] = cz; zv[3] = cz;
  } else {
    const float* fb = Fhp + base;
#pragma unroll
    for (int q = 0; q < 4; ++q) zv[q] = a0 * *(const f32x4*)(fb + q * 4);
    if (nact > 1) {
#pragma unroll
      for (int q = 0; q < 4; ++q) zv[q] += a1 * *(const f32x4*)(fb + SLOT + q * 4);
    }
    if (nact > 2) {
#pragma unroll
      for (int q = 0; q < 4; ++q) zv[q] += a2 * *(const f32x4*)(fb + 2 * SLOT + q * 4);
    }
    if (nact > 3) {
#pragma unroll
      for (int q = 0; q < 4; ++q) zv[q] += a3 * *(const f32x4*)(fb + 3 * SLOT + q * 4);
    }
    if (nact > 4) {
#pragma unroll
      for (int q = 0; q < 4; ++q) zv[q] += a4 * *(const f32x4*)(fb + 4 * SLOT + q * 4);
    }
  }

  // ---- own-row staging: mask-merged bf16 scatter into swizzled A-tile ----
#pragma unroll
  for (int m2 = 0; m2 < 4; ++m2)
#pragma unroll
    for (int rr = 0; rr < 4; ++rr) {
      int p = (m2 << 4) + (lhi << 2) + rr;       // elem index m2*4+rr <-> pixel p
      int px = p & 31, row = 1 + (p >> 5);
      int sg = (colc >> 3) ^ (px & 7);
      u16 w;
      if (mk_s[p])
        w = xsw[(size_t)(gpix0 + p) * 128 + (sg << 3) + (colc & 7)];
      else
        w = f2bf(zv[m2][rr]);
      *(u16*)(As + row * 8704 + ((px + 1) << 8) + (sg << 4) + ((colc & 7) << 1)) = w;
    }

  // ---- halo staging: rows y0-1 and y0+2, coalesced short8 combine from FhH ----
#pragma unroll
  for (int uu = 0; uu < 2; ++uu) {
    int u = (uu << 9) + tid;                     // 1024 units = 2 rows * 32 px * 16 grp
    int row = (u >> 9) * 3;                      // tile row 0 or 3
    int gy = y0 - 1 + row;
    int idx = u & 511;
    int px = idx >> 4, grp = idx & 15;
    char* dst = As + row * 8704 + ((px + 1) << 8) + ((grp ^ (px & 7)) << 4);
    short8 w = {0, 0, 0, 0, 0, 0, 0, 0};
    if ((unsigned)gy < 32u) {
      int gpix = (n << 10) + (gy << 5) + px;
      size_t off = (size_t)gpix * 128 + (size_t)((grp ^ (px & 7)) << 3);
      if (mask_[gpix]) {
        w = *(const short8*)(xsw + off);
      } else if (e == 0) {
#pragma unroll
        for (int i = 0; i < 8; ++i) w[i] = (short)0x3C00;   // bf16(1/128)
      } else {
        f32x4 va, vb;
        short8 h = *(const short8*)(FhH + off);
#pragma unroll
        for (int i = 0; i < 4; ++i) { va[i] = a0 * bf2f((u16)h[i]); vb[i] = a0 * bf2f((u16)h[4 + i]); }
        if (nact > 1) {
          h = *(const short8*)(FhH + SLOT + off);
#pragma unroll
          for (int i = 0; i < 4; ++i) { va[i] += a1 * bf2f((u16)h[i]); vb[i] += a1 * bf2f((u16)h[4 + i]); }
        }
        if (nact > 2) {
          h = *(const short8*)(FhH + 2 * (size_t)SLOT + off);
#pragma unroll
          for (int i = 0; i < 4; ++i) { va[i] += a2 * bf2f((u16)h[i]); vb[i] += a2 * bf2f((u16)h[4 + i]); }
        }
        if (nact > 3) {
          h = *(const short8*)(FhH + 3 * (size_t)SLOT + off);
#pragma unroll
          for (int i = 0; i < 4; ++i) { va[i] += a3 * bf2f((u16)h[i]); vb[i] += a3 * bf2f((u16)h[4 + i]); }
        }
        if (nact > 4) {
          h = *(const short8*)(FhH + 4 * (size_t)SLOT + off);
#pragma unroll
          for (int i = 0; i < 4; ++i) { va[i] += a4 * bf2f((u16)h[i]); vb[i] += a4 * bf2f((u16)h[4 + i]); }
        }
#pragma unroll
        for (int i = 0; i < 4; ++i) { w[i] = (short)f2bf(va[i]); w[4 + i] = (short)f2bf(vb[i]); }
      }
    }
    *(short8*)dst = w;
  }
  if (tid < 128) {                               // zero pads: cols 0 and 33, 4 rows
    int r = tid >> 5, cc = tid & 31;
    int col = (cc < 16) ? 0 : 33, gc = cc & 15;
    f32x4 zz = {0.f, 0.f, 0.f, 0.f};
    *(f32x4*)(As + r * 8704 + (col << 8) + (gc << 4)) = zz;
  }
  __syncthreads();

  // ---- CONV: 144 MFMAs/wave off the LDS tile; B frags from global (L2-hot) ----
  f32x4 acc[4];
  {
    const f32x4 z4 = {0.f, 0.f, 0.f, 0.f};
    acc[0] = z4; acc[1] = z4; acc[2] = z4; acc[3] = z4;
  }
#pragma unroll
  for (int o = 0; o < 9; ++o) {
    const int dy = o / 3, dx = o % 3;
    short8 bfr[4];
#pragma unroll
    for (int kk = 0; kk < 4; ++kk)
      bfr[kk] = *(const short8*)(Wb + o * 16384 + colc * 128 + ((kk << 2) + lhi) * 8);
#pragma unroll
    for (int kk = 0; kk < 4; ++kk) {
      const int kg = (kk << 2) + lhi;
#pragma unroll
      for (int m2 = 0; m2 < 4; ++m2) {
        int p = (m2 << 4) + llo;
        int r = (p >> 5) + dy, cl = (p & 31) + dx;
        int sg = kg ^ ((cl - 1) & 7);
        short8 af = *(const short8*)(As + r * 8704 + (cl << 8) + (sg << 4));
        acc[m2] = __builtin_amdgcn_mfma_f32_16x16x32_bf16(af, bfr[kk], acc[m2], 0, 0, 0);
      }
    }
  }

  // ---- epilogue: damp, channel-softmax(128), fnew, G, gram/res partials ----
  const float bc = bias[colc];
#pragma unroll
  for (int m2 = 0; m2 < 4; ++m2)
#pragma unroll
    for (int rr = 0; rr < 4; ++rr)
      acc[m2][rr] = 0.1f * zv[m2][rr] + 0.9f * (acc[m2][rr] + bc);
#pragma unroll
  for (int m2 = 0; m2 < 4; ++m2)
#pragma unroll
    for (int rr = 0; rr < 4; ++rr) {
      float v = acc[m2][rr];
      v = fmaxf(v, __shfl_xor(v, 1)); v = fmaxf(v, __shfl_xor(v, 2));
      v = fmaxf(v, __shfl_xor(v, 4)); v = fmaxf(v, __shfl_xor(v, 8));
      if (llo == 0) rowmax_s[((m2 << 4) + (lhi << 2) + rr) * 8 + wc] = v;
    }
  __syncthreads();
#pragma unroll
  for (int m2 = 0; m2 < 4; ++m2)
#pragma unroll
    for (int rr = 0; rr < 4; ++rr) {
      int p = (m2 << 4) + (lhi << 2) + rr;
      f32x4 m0 = *(const f32x4*)&rowmax_s[p * 8];
      f32x4 m1 = *(const f32x4*)&rowmax_s[p * 8 + 4];
      float M = fmaxf(fmaxf(fmaxf(m0[0], m0[1]), fmaxf(m0[2], m0[3])),
                      fmaxf(fmaxf(m1[0], m1[1]), fmaxf(m1[2], m1[3])));
      float ev = __expf(acc[m2][rr] - M);
      acc[m2][rr] = ev;
      float s = ev;
      s += __shfl_xor(s, 1); s += __shfl_xor(s, 2);
      s += __shfl_xor(s, 4); s += __shfl_xor(s, 8);
      if (llo == 0) rowsum_s[p * 8 + wc] = s;
    }
  __syncthreads();

  float sd = 0.f, sf = 0.f;
  float gd16[16];
#pragma unroll
  for (int m2 = 0; m2 < 4; ++m2) {
    f32x4 fr;
#pragma unroll
    for (int rr = 0; rr < 4; ++rr) {
      int p = (m2 << 4) + (lhi << 2) + rr;
      f32x4 s0 = *(const f32x4*)&rowsum_s[p * 8];
      f32x4 s1 = *(const f32x4*)&rowsum_s[p * 8 + 4];
      float S = s0[0] + s0[1] + s0[2] + s0[3] + s1[0] + s1[1] + s1[2] + s1[3];
      float fnew = acc[m2][rr] * (1.0f / S);
      fr[rr] = fnew;
      float gd = fnew - zv[m2][rr];
      gd16[m2 * 4 + rr] = gd;
      sd += gd * gd; sf += fnew * fnew;
      int px = p & 31;
      FhH[(size_t)slot * SLOT + (size_t)(gpix0 + p) * 128 +
          ((((colc >> 3) ^ (px & 7)) << 3) | (colc & 7))] = f2bf(fnew);
    }
    *(f32x4*)(Fhp + (size_t)slot * SLOT + base + m2 * 4) = fr;   // 64B/thread total
  }
  {
    short8 h0, h1;
#pragma unroll
    for (int i = 0; i < 8; ++i) { h0[i] = (short)f2bf(gd16[i]); h1[i] = (short)f2bf(gd16[8 + i]); }
    u16* Gs = Gp + (size_t)slot * SLOT + base;
    *(short8*)(Gs) = h0;
    *(short8*)(Gs + 8) = h1;
    const int jmax = e < 4 ? e : 4;              // valid slots this iteration
    float gacc[5];
#pragma unroll
    for (int j = 0; j < 5; ++j) {
      if (j > jmax) { gacc[j] = 0.f; continue; }
      if (j == slot) {
        float a = 0.f;
#pragma unroll
        for (int i = 0; i < 16; ++i) a += gd16[i] * gd16[i];
        gacc[j] = a;
      } else {
        short8 q0 = *(const short8*)(Gp + (size_t)j * SLOT + base);
        short8 q1 = *(const short8*)(Gp + (size_t)j * SLOT + base + 8);
        float a = 0.f;
#pragma unroll
        for (int i = 0; i < 8; ++i)
          a += gd16[i] * bf2f((u16)q0[i]) + gd16[8 + i] * bf2f((u16)q1[i]);
        gacc[j] = a;
      }
    }
    float vals[7] = {gacc[0], gacc[1], gacc[2], gacc[3], gacc[4], sd, sf};
#pragma unroll
    for (int i = 0; i < 7; ++i) {
      float v = vals[i];
#pragma unroll
      for (int off = 1; off < 64; off <<= 1) v += __shfl_xor(v, off);
      if (lane == 0) red[wc * 8 + i] = v;
    }
  }
  __syncthreads();
  if (tid < 7) {
    float s = 0.f;
#pragma unroll
    for (int w = 0; w < 8; ++w) s += red[w * 8 + tid];
    if (tid < 5)       gpart[(size_t)lbid * 5 + tid] = s;
    else if (tid == 5) resp[lbid * 2] = s;
    else               resp[lbid * 2 + 1] = s;
  }
}

// ---------------- final: Fhp[last_slot] packed -> d_out NCHW f32
__global__ void __launch_bounds__(512) k_out(const float* __restrict__ Fhp,
    const Ctrl* __restrict__ ctrl, float* __restrict__ out)
{
  __shared__ float T[64 * 129];
  int slot = ctrl->last_slot;
  const int tid = threadIdx.x;
  const int wc = tid >> 6, lane = tid & 63;
  const int lhi = lane >> 4, llo = lane & 15;
  const int bhw = blockIdx.x;
  const int lbid = ((bhw & 7) << 6) + (bhw >> 3);
  const int n = lbid >> 4, y0 = (lbid & 15) << 1;
  const size_t base = (size_t)slot * SLOT + ((size_t)lbid * 512 + tid) * 16;
#pragma unroll
  for (int m2 = 0; m2 < 4; ++m2) {
    f32x4 v = *(const f32x4*)(Fhp + base + m2 * 4);
#pragma unroll
    for (int rr = 0; rr < 4; ++rr) {
      int p = (m2 << 4) + (lhi << 2) + rr;
      T[p * 129 + (wc << 4) + llo] = v[rr];
    }
  }
  __syncthreads();
  int c = tid >> 2, q = tid & 3;
  int row = q >> 1, xs = (q & 1) << 4;
  float* ob = out + (((size_t)(n << 7) + c) << 10) + ((y0 + row) << 5) + xs;
#pragma unroll
  for (int i2 = 0; i2 < 4; ++i2) {
    f32x4 v;
#pragma unroll
    for (int i = 0; i < 4; ++i) v[i] = T[((row << 5) + xs + (i2 << 2) + i) * 129 + c];
    *(f32x4*)(ob + (i2 << 2)) = v;
  }
}

extern "C" void kernel_launch(void* const* d_in, const int* in_sizes, int n_in,
                              void* d_out, int out_size, void* d_ws, size_t ws_size,
                              hipStream_t stream) {
  const float* x    = (const float*)d_in[0];   // [32,128,32,32]
  const float* W    = (const float*)d_in[1];   // [128,128,3,3]
  const float* bias = (const float*)d_in[2];   // [128]
  const int*   mask = (const int*)d_in[3];     // [32,1,32,32]
  float* out = (float*)d_out;
  char* ws = (char*)d_ws;

  float* Fhp   = (float*)(ws + 0);             // 83,886,080 (packed f32)
  u16*   FhH   = (u16*)(ws + 83886080);        // 41,943,040 (bf16 NHWC swizzled)
  u16*   Gp    = (u16*)(ws + 125829120);       // 41,943,040 (packed bf16)
  u16*   xsw   = (u16*)(ws + 167772160);       // 8,388,608
  u16*   Wb    = (u16*)(ws + 176160768);       // 294,912
  float* gram  = (float*)(ws + 176455680);     // 3,200
  float* gpart = (float*)(ws + 176458880);     // 10,240
  float* resp  = (float*)(ws + 176469120);     // 4,096
  Ctrl*  ctrl  = (Ctrl*)(ws + 176473216);

  k_prepw<<<576, 256, 0, stream>>>(W, Wb, ctrl);
  k_prepx<<<2048, 256, 0, stream>>>(x, xsw);
  for (int e = 0; e < 50; ++e)
    k_iter<<<512, 512, 0, stream>>>(e, xsw, mask, Wb, bias,
                                    Fhp, FhH, Gp, gram, gpart, resp, ctrl);
  k_out<<<512, 512, 0, stream>>>(Fhp, ctrl, out);
  (void)in_sizes; (void)n_in; (void)out_size; (void)ws_size;
}

// Round 8
// 468.674 us; speedup vs baseline: 1.7335x; 1.3450x over previous
//
#include <hip/hip_runtime.h>

// MON forward-backward splitting via Anderson acceleration, MI355X/gfx950.
// R7: R6 with the register-allocator occupancy TARGET fixed. Diagnosis: with
//     39.9KB LDS the backend targets 4 blocks/CU = 8 waves/SIMD = 64 VGPRs and
//     spills ~160MB/iter to scratch (WRITE_SIZE 203MB vs 42MB logical).
//     __launch_bounds__(512,N) only sets the FLOOR (cap); amdgpu_waves_per_eu's
//     max=4 lowers the TARGET so the kernel gets ~128 VGPRs spill-free.

typedef unsigned short u16;
using short8 = __attribute__((ext_vector_type(8))) short;
using f32x4  = __attribute__((ext_vector_type(4))) float;

#define SLOT 4194304              // elements per history slot (32768 px * 128 ch)

struct Ctrl { int done; int last_slot; };

__device__ __forceinline__ u16 f2bf(float f) {
  unsigned u = __builtin_bit_cast(unsigned, f);
  unsigned r = (u + 0x7FFFu + ((u >> 16) & 1u)) >> 16;   // RNE, finite inputs
  return (u16)r;
}
__device__ __forceinline__ float bf2f(u16 h) {
  unsigned u = ((unsigned)h) << 16;
  return __builtin_bit_cast(float, u);
}

// ---------------- W[cout][cin][ky][kx] f32 -> Wb[o][cout][cin] bf16; ctrl init
__global__ void __launch_bounds__(256) k_prepw(const float* __restrict__ W,
    u16* __restrict__ Wb, Ctrl* ctrl) {
  if (blockIdx.x == 0 && threadIdx.x == 0) { ctrl->done = 0; ctrl->last_slot = 4; }
  int t = blockIdx.x * 256 + threadIdx.x;       // 9*128*128 threads
  int o = t >> 14;
  int rem = t & 16383;
  int cout = rem >> 7, cin = rem & 127;
  float v = W[(size_t)cout * 1152 + (size_t)cin * 9 + o];
  Wb[(size_t)o * 16384 + (size_t)cout * 128 + cin] = f2bf(v);
}

// ---------------- x NCHW f32 -> xsw bf16 swizzled NHWC
__global__ void __launch_bounds__(256) k_prepx(const float* __restrict__ x,
    u16* __restrict__ xsw) {
  int t = blockIdx.x * 256 + threadIdx.x;       // 524288 threads
  int g = t >> 15, p = t & 32767;
  int nb = p >> 10, gp = p & 1023, px = p & 31;
  short8 xv;
#pragma unroll
  for (int u = 0; u < 8; ++u) {
    float v = x[(size_t)nb * 131072 + (size_t)(g * 8 + u) * 1024 + gp];
    xv[u] = (short)f2bf(v);
  }
  *(short8*)(xsw + (size_t)p * 128 + (size_t)((g ^ (px & 7)) << 3)) = xv;
}

// ---------------- one Anderson iteration, fully fused ----------------
// 512 blocks x 512 threads; logical block lbid = 2-row strip (n = lbid>>4, y0 = (lbid&15)*2).
// Thread owns 16 (pixel,channel) elems in the MFMA C/D mapping; z kept in registers.
// Packed layout: elem (slot, lbid, tid, m2*4+rr) <-> pixel p=m2*16+lhi*4+rr, ch=wc*16+llo.
__global__ void __launch_bounds__(512)
__attribute__((amdgpu_waves_per_eu(2, 4)))
k_iter(
    const int e,
    const u16* __restrict__ xsw, const int* __restrict__ mask_,
    const u16* __restrict__ Wb, const float* __restrict__ bias,
    float* __restrict__ Fhp, u16* __restrict__ FhH, u16* __restrict__ Gp,
    float* __restrict__ gram, float* __restrict__ gpart,
    float* __restrict__ resp, Ctrl* __restrict__ ctrl)
{
  __shared__ char smem[39552];
  char*  As       = smem;                        // 4 rows * 34 cols * 256B = 34816
  float* rowmax_s = (float*)(smem + 34816);      // [64][8] = 2048
  float* rowsum_s = (float*)(smem + 36864);      // 2048
  float* red      = (float*)(smem + 38912);      // 8 waves * 8 = 256
  float* alpha_s  = (float*)(smem + 39168);      // 5
  float* res_s    = (float*)(smem + 39188);      // 1
  int*   mk_s     = (int*)(smem + 39296);        // 64

  if (ctrl->done) return;

  const int tid = threadIdx.x;
  const int wc = tid >> 6, lane = tid & 63;
  const int lhi = lane >> 4, llo = lane & 15;
  const int bhw = blockIdx.x;
  const int lbid = ((bhw & 7) << 6) + (bhw >> 3);    // XCD chunk swizzle (512=8*64)
  const int n = lbid >> 4, y0 = (lbid & 15) << 1;
  const int gpix0 = (n << 10) + (y0 << 5);
  const int colc = (wc << 4) + llo;
  const int slot = e % 5;
  const int nact = e < 5 ? e : 5;
  const size_t base = ((size_t)lbid * 512 + tid) * 16;

  // ---- res gate (cond before body e uses res of eval e-1) ----
  if (e >= 3) {
    if (tid < 64) {
      float sd = 0.f, sf = 0.f;
      for (int i = tid; i < 512; i += 64) { sd += resp[2 * i]; sf += resp[2 * i + 1]; }
#pragma unroll
      for (int off = 1; off < 64; off <<= 1) { sd += __shfl_xor(sd, off); sf += __shfl_xor(sf, off); }
      if (tid == 0) res_s[0] = sqrtf(sd) / (1e-5f + sqrtf(sf));
    }
    __syncthreads();
    if (res_s[0] < 1e-5f) {                      // identical decision in every block
      if (tid == 0) { ctrl->done = 1; ctrl->last_slot = (e - 1) % 5; }
      return;
    }
  }

  // ---- masks for own 64 px; fold gram row/col of slot (e-1)%5 ----
  if (tid < 64) mk_s[tid] = mask_[gpix0 + tid];
  if (e >= 1 && tid >= 64 && tid < 69) {
    int j = tid - 64;
    float s = 0.f;
#pragma unroll
    for (int c = 0; c < 16; ++c) s += gpart[(size_t)((n << 4) + c) * 5 + j];
    int sp = (e - 1) % 5;
    gram[n * 25 + sp * 5 + j] = s;               // all 16 blocks of image n write
    gram[n * 25 + j * 5 + sp] = s;               // identical values: benign
  }
  __syncthreads();
  if (e >= 2) {
    if (tid == 0) {                              // bordered 6x6 solve, f32 GE w/ pivot
      float A[6][7];
      for (int i = 0; i < 5; ++i)
        for (int j = 0; j < 5; ++j)
          A[i + 1][j + 1] = (i < nact && j < nact)
              ? gram[n * 25 + i * 5 + j] + ((i == j) ? 1e-4f : 0.f)
              : ((i == j) ? 1.f : 0.f);
      A[0][0] = 0.f;
      for (int j = 0; j < 5; ++j) { float aj = (j < nact) ? 1.f : 0.f; A[0][j + 1] = aj; A[j + 1][0] = aj; }
      A[0][6] = 1.f;
      for (int i = 1; i < 6; ++i) A[i][6] = 0.f;
      for (int c = 0; c < 6; ++c) {
        int p = c; float mx = fabsf(A[c][c]);
        for (int r = c + 1; r < 6; ++r) { float v = fabsf(A[r][c]); if (v > mx) { mx = v; p = r; } }
        if (p != c) for (int q = c; q < 7; ++q) { float tmp = A[c][q]; A[c][q] = A[p][q]; A[p][q] = tmp; }
        float piv = A[c][c];
        for (int r = c + 1; r < 6; ++r) {
          float fr = A[r][c] / piv;
          for (int q = c; q < 7; ++q) A[r][q] -= fr * A[c][q];
        }
      }
      float sol[6];
      for (int r = 5; r >= 0; --r) {
        float s = A[r][6];
        for (int q = r + 1; q < 6; ++q) s -= A[r][q] * sol[q];
        sol[r] = s / A[r][r];
      }
      for (int j = 0; j < 5; ++j) alpha_s[j] = sol[j + 1];
    }
  } else if (tid < 5) {
    alpha_s[tid] = (tid == 0) ? 1.f : 0.f;       // e==1: xnew = F0 (e==0 ignores)
  }
  __syncthreads();

  float a0 = 1.f, a1 = 0.f, a2 = 0.f, a3 = 0.f, a4 = 0.f;
  if (e >= 1) { a0 = alpha_s[0]; a1 = alpha_s[1]; a2 = alpha_s[2]; a3 = alpha_s[3]; a4 = alpha_s[4]; }

  // ---- FX own: z = sum_j alpha_j Fh_j, vectorized from packed layout ----
  f32x4 zv[4];
  if (e == 0) {
    const f32x4 cz = {0.0078125f, 0.0078125f, 0.0078125f, 0.0078125f};
    zv[0] = cz; zv[1] = cz; zv[2] = cz; zv[3] = cz;
  } else {
    const float* fb = Fhp + base;
#pragma unroll
    for (int q = 0; q < 4; ++q) zv[q] = a0 * *(const f32x4*)(fb + q * 4);
    if (nact > 1) {
#pragma unroll
      for (int q = 0; q < 4; ++q) zv[q] += a1 * *(const f32x4*)(fb + SLOT + q * 4);
    }
    if (nact > 2) {
#pragma unroll
      for (int q = 0; q < 4; ++q) zv[q] += a2 * *(const f32x4*)(fb + 2 * SLOT + q * 4);
    }
    if (nact > 3) {
#pragma unroll
      for (int q = 0; q < 4; ++q) zv[q] += a3 * *(const f32x4*)(fb + 3 * SLOT + q * 4);
    }
    if (nact > 4) {
#pragma unroll
      for (int q = 0; q < 4; ++q) zv[q] += a4 * *(const f32x4*)(fb + 4 * SLOT + q * 4);
    }
  }

  // ---- own-row staging: mask-merged bf16 scatter into swizzled A-tile ----
#pragma unroll
  for (int m2 = 0; m2 < 4; ++m2)
#pragma unroll
    for (int rr = 0; rr < 4; ++rr) {
      int p = (m2 << 4) + (lhi << 2) + rr;       // elem index m2*4+rr <-> pixel p
      int px = p & 31, row = 1 + (p >> 5);
      int sg = (colc >> 3) ^ (px & 7);
      u16 w;
      if (mk_s[p])
        w = xsw[(size_t)(gpix0 + p) * 128 + (sg << 3) + (colc & 7)];
      else
        w = f2bf(zv[m2][rr]);
      *(u16*)(As + row * 8704 + ((px + 1) << 8) + (sg << 4) + ((colc & 7) << 1)) = w;
    }

  // ---- halo staging: rows y0-1 and y0+2, coalesced short8 combine from FhH ----
#pragma unroll
  for (int uu = 0; uu < 2; ++uu) {
    int u = (uu << 9) + tid;                     // 1024 units = 2 rows * 32 px * 16 grp
    int row = (u >> 9) * 3;                      // tile row 0 or 3
    int gy = y0 - 1 + row;
    int idx = u & 511;
    int px = idx >> 4, grp = idx & 15;
    char* dst = As + row * 8704 + ((px + 1) << 8) + ((grp ^ (px & 7)) << 4);
    short8 w = {0, 0, 0, 0, 0, 0, 0, 0};
    if ((unsigned)gy < 32u) {
      int gpix = (n << 10) + (gy << 5) + px;
      size_t off = (size_t)gpix * 128 + (size_t)((grp ^ (px & 7)) << 3);
      if (mask_[gpix]) {
        w = *(const short8*)(xsw + off);
      } else if (e == 0) {
#pragma unroll
        for (int i = 0; i < 8; ++i) w[i] = (short)0x3C00;   // bf16(1/128)
      } else {
        f32x4 va, vb;
        short8 h = *(const short8*)(FhH + off);
#pragma unroll
        for (int i = 0; i < 4; ++i) { va[i] = a0 * bf2f((u16)h[i]); vb[i] = a0 * bf2f((u16)h[4 + i]); }
        if (nact > 1) {
          h = *(const short8*)(FhH + SLOT + off);
#pragma unroll
          for (int i = 0; i < 4; ++i) { va[i] += a1 * bf2f((u16)h[i]); vb[i] += a1 * bf2f((u16)h[4 + i]); }
        }
        if (nact > 2) {
          h = *(const short8*)(FhH + 2 * (size_t)SLOT + off);
#pragma unroll
          for (int i = 0; i < 4; ++i) { va[i] += a2 * bf2f((u16)h[i]); vb[i] += a2 * bf2f((u16)h[4 + i]); }
        }
        if (nact > 3) {
          h = *(const short8*)(FhH + 3 * (size_t)SLOT + off);
#pragma unroll
          for (int i = 0; i < 4; ++i) { va[i] += a3 * bf2f((u16)h[i]); vb[i] += a3 * bf2f((u16)h[4 + i]); }
        }
        if (nact > 4) {
          h = *(const short8*)(FhH + 4 * (size_t)SLOT + off);
#pragma unroll
          for (int i = 0; i < 4; ++i) { va[i] += a4 * bf2f((u16)h[i]); vb[i] += a4 * bf2f((u16)h[4 + i]); }
        }
#pragma unroll
        for (int i = 0; i < 4; ++i) { w[i] = (short)f2bf(va[i]); w[4 + i] = (short)f2bf(vb[i]); }
      }
    }
    *(short8*)dst = w;
  }
  if (tid < 128) {                               // zero pads: cols 0 and 33, 4 rows
    int r = tid >> 5, cc = tid & 31;
    int col = (cc < 16) ? 0 : 33, gc = cc & 15;
    f32x4 zz = {0.f, 0.f, 0.f, 0.f};
    *(f32x4*)(As + r * 8704 + (col << 8) + (gc << 4)) = zz;
  }
  __syncthreads();

  // ---- CONV: 144 MFMAs/wave off the LDS tile; B frags from global (L2-hot) ----
  f32x4 acc[4];
  {
    const f32x4 z4 = {0.f, 0.f, 0.f, 0.f};
    acc[0] = z4; acc[1] = z4; acc[2] = z4; acc[3] = z4;
  }
#pragma unroll
  for (int o = 0; o < 9; ++o) {
    const int dy = o / 3, dx = o % 3;
    short8 bfr[4];
#pragma unroll
    for (int kk = 0; kk < 4; ++kk)
      bfr[kk] = *(const short8*)(Wb + o * 16384 + colc * 128 + ((kk << 2) + lhi) * 8);
#pragma unroll
    for (int kk = 0; kk < 4; ++kk) {
      const int kg = (kk << 2) + lhi;
#pragma unroll
      for (int m2 = 0; m2 < 4; ++m2) {
        int p = (m2 << 4) + llo;
        int r = (p >> 5) + dy, cl = (p & 31) + dx;
        int sg = kg ^ ((cl - 1) & 7);
        short8 af = *(const short8*)(As + r * 8704 + (cl << 8) + (sg << 4));
        acc[m2] = __builtin_amdgcn_mfma_f32_16x16x32_bf16(af, bfr[kk], acc[m2], 0, 0, 0);
      }
    }
  }

  // ---- epilogue: damp, channel-softmax(128), fnew, G, gram/res partials ----
  const float bc = bias[colc];
#pragma unroll
  for (int m2 = 0; m2 < 4; ++m2)
#pragma unroll
    for (int rr = 0; rr < 4; ++rr)
      acc[m2][rr] = 0.1f * zv[m2][rr] + 0.9f * (acc[m2][rr] + bc);
#pragma unroll
  for (int m2 = 0; m2 < 4; ++m2)
#pragma unroll
    for (int rr = 0; rr < 4; ++rr) {
      float v = acc[m2][rr];
      v = fmaxf(v, __shfl_xor(v, 1)); v = fmaxf(v, __shfl_xor(v, 2));
      v = fmaxf(v, __shfl_xor(v, 4)); v = fmaxf(v, __shfl_xor(v, 8));
      if (llo == 0) rowmax_s[((m2 << 4) + (lhi << 2) + rr) * 8 + wc] = v;
    }
  __syncthreads();
#pragma unroll
  for (int m2 = 0; m2 < 4; ++m2)
#pragma unroll
    for (int rr = 0; rr < 4; ++rr) {
      int p = (m2 << 4) + (lhi << 2) + rr;
      f32x4 m0 = *(const f32x4*)&rowmax_s[p * 8];
      f32x4 m1 = *(const f32x4*)&rowmax_s[p * 8 + 4];
      float M = fmaxf(fmaxf(fmaxf(m0[0], m0[1]), fmaxf(m0[2], m0[3])),
                      fmaxf(fmaxf(m1[0], m1[1]), fmaxf(m1[2], m1[3])));
      float ev = __expf(acc[m2][rr] - M);
      acc[m2][rr] = ev;
      float s = ev;
      s += __shfl_xor(s, 1); s += __shfl_xor(s, 2);
      s += __shfl_xor(s, 4); s += __shfl_xor(s, 8);
      if (llo == 0) rowsum_s[p * 8 + wc] = s;
    }
  __syncthreads();

  float sd = 0.f, sf = 0.f;
  float gd16[16];
#pragma unroll
  for (int m2 = 0; m2 < 4; ++m2) {
    f32x4 fr;
#pragma unroll
    for (int rr = 0; rr < 4; ++rr) {
      int p = (m2 << 4) + (lhi << 2) + rr;
      f32x4 s0 = *(const f32x4*)&rowsum_s[p * 8];
      f32x4 s1 = *(const f32x4*)&rowsum_s[p * 8 + 4];
      float S = s0[0] + s0[1] + s0[2] + s0[3] + s1[0] + s1[1] + s1[2] + s1[3];
      float fnew = acc[m2][rr] * (1.0f / S);
      fr[rr] = fnew;
      float gd = fnew - zv[m2][rr];
      gd16[m2 * 4 + rr] = gd;
      sd += gd * gd; sf += fnew * fnew;
      int px = p & 31;
      FhH[(size_t)slot * SLOT + (size_t)(gpix0 + p) * 128 +
          ((((colc >> 3) ^ (px & 7)) << 3) | (colc & 7))] = f2bf(fnew);
    }
    *(f32x4*)(Fhp + (size_t)slot * SLOT + base + m2 * 4) = fr;   // 64B/thread total
  }
  {
    short8 h0, h1;
#pragma unroll
    for (int i = 0; i < 8; ++i) { h0[i] = (short)f2bf(gd16[i]); h1[i] = (short)f2bf(gd16[8 + i]); }
    u16* Gs = Gp + (size_t)slot * SLOT + base;
    *(short8*)(Gs) = h0;
    *(short8*)(Gs + 8) = h1;
    const int jmax = e < 4 ? e : 4;              // valid slots this iteration
    float gacc[5];
#pragma unroll
    for (int j = 0; j < 5; ++j) {
      if (j > jmax) { gacc[j] = 0.f; continue; }
      if (j == slot) {
        float a = 0.f;
#pragma unroll
        for (int i = 0; i < 16; ++i) a += gd16[i] * gd16[i];
        gacc[j] = a;
      } else {
        short8 q0 = *(const short8*)(Gp + (size_t)j * SLOT + base);
        short8 q1 = *(const short8*)(Gp + (size_t)j * SLOT + base + 8);
        float a = 0.f;
#pragma unroll
        for (int i = 0; i < 8; ++i)
          a += gd16[i] * bf2f((u16)q0[i]) + gd16[8 + i] * bf2f((u16)q1[i]);
        gacc[j] = a;
      }
    }
    float vals[7] = {gacc[0], gacc[1], gacc[2], gacc[3], gacc[4], sd, sf};
#pragma unroll
    for (int i = 0; i < 7; ++i) {
      float v = vals[i];
#pragma unroll
      for (int off = 1; off < 64; off <<= 1) v += __shfl_xor(v, off);
      if (lane == 0) red[wc * 8 + i] = v;
    }
  }
  __syncthreads();
  if (tid < 7) {
    float s = 0.f;
#pragma unroll
    for (int w = 0; w < 8; ++w) s += red[w * 8 + tid];
    if (tid < 5)       gpart[(size_t)lbid * 5 + tid] = s;
    else if (tid == 5) resp[lbid * 2] = s;
    else               resp[lbid * 2 + 1] = s;
  }
}

// ---------------- final: Fhp[last_slot] packed -> d_out NCHW f32
__global__ void __launch_bounds__(512) k_out(const float* __restrict__ Fhp,
    const Ctrl* __restrict__ ctrl, float* __restrict__ out)
{
  __shared__ float T[64 * 129];
  int slot = ctrl->last_slot;
  const int tid = threadIdx.x;
  const int wc = tid >> 6, lane = tid & 63;
  const int lhi = lane >> 4, llo = lane & 15;
  const int bhw = blockIdx.x;
  const int lbid = ((bhw & 7) << 6) + (bhw >> 3);
  const int n = lbid >> 4, y0 = (lbid & 15) << 1;
  const size_t base = (size_t)slot * SLOT + ((size_t)lbid * 512 + tid) * 16;
#pragma unroll
  for (int m2 = 0; m2 < 4; ++m2) {
    f32x4 v = *(const f32x4*)(Fhp + base + m2 * 4);
#pragma unroll
    for (int rr = 0; rr < 4; ++rr) {
      int p = (m2 << 4) + (lhi << 2) + rr;
      T[p * 129 + (wc << 4) + llo] = v[rr];
    }
  }
  __syncthreads();
  int c = tid >> 2, q = tid & 3;
  int row = q >> 1, xs = (q & 1) << 4;
  float* ob = out + (((size_t)(n << 7) + c) << 10) + ((y0 + row) << 5) + xs;
#pragma unroll
  for (int i2 = 0; i2 < 4; ++i2) {
    f32x4 v;
#pragma unroll
    for (int i = 0; i < 4; ++i) v[i] = T[((row << 5) + xs + (i2 << 2) + i) * 129 + c];
    *(f32x4*)(ob + (i2 << 2)) = v;
  }
}

extern "C" void kernel_launch(void* const* d_in, const int* in_sizes, int n_in,
                              void* d_out, int out_size, void* d_ws, size_t ws_size,
                              hipStream_t stream) {
  const float* x    = (const float*)d_in[0];   // [32,128,32,32]
  const float* W    = (const float*)d_in[1];   // [128,128,3,3]
  const float* bias = (const float*)d_in[2];   // [128]
  const int*   mask = (const int*)d_in[3];     // [32,1,32,32]
  float* out = (float*)d_out;
  char* ws = (char*)d_ws;

  float* Fhp   = (float*)(ws + 0);             // 83,886,080 (packed f32)
  u16*   FhH   = (u16*)(ws + 83886080);        // 41,943,040 (bf16 NHWC swizzled)
  u16*   Gp    = (u16*)(ws + 125829120);       // 41,943,040 (packed bf16)
  u16*   xsw   = (u16*)(ws + 167772160);       // 8,388,608
  u16*   Wb    = (u16*)(ws + 176160768);       // 294,912
  float* gram  = (float*)(ws + 176455680);     // 3,200
  float* gpart = (float*)(ws + 176458880);     // 10,240
  float* resp  = (float*)(ws + 176469120);     // 4,096
  Ctrl*  ctrl  = (Ctrl*)(ws + 176473216);

  k_prepw<<<576, 256, 0, stream>>>(W, Wb, ctrl);
  k_prepx<<<2048, 256, 0, stream>>>(x, xsw);
  for (int e = 0; e < 50; ++e)
    k_iter<<<512, 512, 0, stream>>>(e, xsw, mask, Wb, bias,
                                    Fhp, FhH, Gp, gram, gpart, resp, ctrl);
  k_out<<<512, 512, 0, stream>>>(Fhp, ctrl, out);
  (void)in_sizes; (void)n_in; (void)out_size; (void)ws_size;
}